// Round 6
// baseline (855.955 us; speedup 1.0000x reference)
//
#include <hip/hip_runtime.h>
#include <hip/hip_bf16.h>

#define FEAT 128
#define NRELS 8
#define SCAN_CHUNK 256

typedef __bf16 bf16_t;
typedef __bf16 bf16x8_t __attribute__((ext_vector_type(8)));
typedef float f32x4 __attribute__((ext_vector_type(4)));

struct __align__(8) PackedEdge { int row; float scale; };  // row = src*8 + rel

static inline size_t align256(size_t x) { return (x + 255) & ~(size_t)255; }

// ---------------------------------------------------------------------------
// W [r][d][f] fp32 -> Wt [f][r*128+d] bf16  (A-operand: m=fout rows, k=r*128+d
// contiguous per row -> 16B vector loads of 8 k-elements).
__global__ void k_convert_w(const float* __restrict__ w, bf16_t* __restrict__ wt) {
    int i = blockIdx.x * blockDim.x + threadIdx.x;
    if (i >= NRELS * FEAT * FEAT) return;
    int r = i >> 14;
    int rem = i & 16383;
    int d = rem >> 7;
    int f = rem & 127;
    wt[(size_t)f * (NRELS * FEAT) + r * FEAT + d] = (bf16_t)w[i];
}

// ---------------------------------------------------------------------------
// Gate: sg[n][r] = sigmoid(sum_d h[n][d]*gw[r][d]); fp32. One wave per node.
__global__ void k_gate(const float* __restrict__ h, const float* __restrict__ gw,
                       float* __restrict__ sg, int ncount) {
    int wv = (int)((blockIdx.x * blockDim.x + threadIdx.x) >> 6);
    int lane = threadIdx.x & 63;
    if (wv >= ncount) return;
    float2 hv = *reinterpret_cast<const float2*>(h + (size_t)wv * FEAT + lane * 2);
    float res[NRELS];
#pragma unroll
    for (int r = 0; r < NRELS; ++r) {
        float2 wvv = *reinterpret_cast<const float2*>(gw + r * FEAT + lane * 2);
        float s = hv.x * wvv.x + hv.y * wvv.y;
#pragma unroll
        for (int off = 32; off; off >>= 1) s += __shfl_xor(s, off, 64);
        res[r] = s;
    }
    if (lane == 0) {
#pragma unroll
        for (int r = 0; r < NRELS; ++r)
            sg[(size_t)wv * NRELS + r] = 1.0f / (1.0f + __expf(-res[r]));
    }
}

// ---------------------------------------------------------------------------
// CSR build over dst
__global__ void k_degree(const int* __restrict__ dstv, int* __restrict__ deg, int nedges) {
    int e = blockIdx.x * blockDim.x + threadIdx.x;
    if (e >= nedges) return;
    atomicAdd(&deg[dstv[e]], 1);
}

__global__ __launch_bounds__(256) void k_scan_block(const int* __restrict__ in,
                                                    int* __restrict__ outv,
                                                    int* __restrict__ bsum, int n) {
    __shared__ int sm[256];
    int t = threadIdx.x;
    int idx = blockIdx.x * SCAN_CHUNK + t;
    int v = (idx < n) ? in[idx] : 0;
    sm[t] = v;
    __syncthreads();
    for (int off = 1; off < 256; off <<= 1) {
        int x = (t >= off) ? sm[t - off] : 0;
        __syncthreads();
        sm[t] += x;
        __syncthreads();
    }
    if (idx < n) outv[idx] = sm[t] - v;
    if (t == 255) bsum[blockIdx.x] = sm[255];
}

__global__ __launch_bounds__(1024) void k_scan_tops(int* __restrict__ bsum, int nb,
                                                    int* __restrict__ rowptr_end) {
    __shared__ int sm[1024];
    int t = threadIdx.x;
    if (nb <= 1024) {
        int v = (t < nb) ? bsum[t] : 0;
        sm[t] = v;
        __syncthreads();
        for (int off = 1; off < 1024; off <<= 1) {
            int x = (t >= off) ? sm[t - off] : 0;
            __syncthreads();
            sm[t] += x;
            __syncthreads();
        }
        if (t < nb) bsum[t] = sm[t] - v;
        if (t == 1023) *rowptr_end = sm[1023];
    } else if (t == 0) {
        int run = 0;
        for (int b = 0; b < nb; ++b) { int v = bsum[b]; bsum[b] = run; run += v; }
        *rowptr_end = run;
    }
}

// Adds block offsets; also writes cursor (a second copy used by k_fill's atomics).
__global__ void k_scan_add(int* __restrict__ rowptr, int* __restrict__ cursor,
                           const int* __restrict__ bsum, int n) {
    int i = blockIdx.x * blockDim.x + threadIdx.x;
    if (i >= n) return;
    int v = rowptr[i] + bsum[i >> 8];
    rowptr[i] = v;
    cursor[i] = v;
}

// Fill packed records {row=src*8+rel, scale} + parallel dst array at CSR slots.
__global__ void k_fill(const int* __restrict__ src, const int* __restrict__ dstv,
                       const int* __restrict__ rel, const float* __restrict__ nrm,
                       const float* __restrict__ sg, int* __restrict__ cursor,
                       PackedEdge* __restrict__ packed, int* __restrict__ pdst,
                       int nedges) {
    int e = blockIdx.x * blockDim.x + threadIdx.x;
    if (e >= nedges) return;
    int d = dstv[e];
    int s = src[e];
    int r = rel[e];
    int pos = atomicAdd(&cursor[d], 1);
    PackedEdge p;
    p.row = s * NRELS + r;
    p.scale = nrm[e] * sg[(size_t)s * NRELS + r];
    packed[pos] = p;
    pdst[pos] = d;
}

// ---------------------------------------------------------------------------
// Fused aggregate + transform. Block = 512 threads (8 waves), 16-node tile.
// Phase A: branchless edge streaming. The tile's merged CSR range [rb,re) is
//   split into 8 contiguous per-wave spans; each wave consumes its span in
//   uniform batches of 8 (tail edges duplicated with scale=0): 8 packed+pdst
//   loads -> 8 independent h-row loads (lane l covers feats l and l+64) ->
//   16 LDS fp32 atomicAdds into the swizzled agg tile [16][1024]. No
//   loop-carried deps; ~2 memory latencies per 8 edges.
//   Swizzle: value (row dl, k kk) lives at float off dl*1024 +
//   (((kk>>2)^(dl&7))<<2) + (kk&3)  -> ds_add 2-way conflicts (free).
// Phase B: wave wv computes out[node=t0+l15][fout=wv*16+lhi*4+i]:
//   K=1024 in 32 mfma_16x16x32 steps; A=Wt (global, L2-hot), B=agg from LDS
//   (2x ds_read_b128 + fp32->bf16 pack). Fused ReLU, float4 stores.
__global__ __launch_bounds__(512, 4) void k_fused(const float* __restrict__ h,
                                                  const bf16_t* __restrict__ wt,
                                                  const PackedEdge* __restrict__ packed,
                                                  const int* __restrict__ pdst,
                                                  const int* __restrict__ rowptr,
                                                  float* __restrict__ out, int nnodes) {
    __shared__ float agg[16 * 1024];           // 64 KiB -> 2 blocks/CU
    const int tile = blockIdx.x;
    const int t0 = tile * 16;
    const int tid = threadIdx.x;
    const int wv = tid >> 6;
    const int lane = tid & 63;

    // zero agg: 4096 float4s / 512 threads = 8 each
#pragma unroll
    for (int i = 0; i < 8; ++i)
        reinterpret_cast<float4*>(agg)[tid + i * 512] = make_float4(0.f, 0.f, 0.f, 0.f);
    __syncthreads();

    // ---------------- Phase A ----------------
    int c0 = t0 < nnodes ? t0 : nnodes;
    int c1 = (t0 + 16) < nnodes ? (t0 + 16) : nnodes;
    int rb = rowptr[c0];
    int re = rowptr[c1];
    int len = re - rb;
    int per = (len + 7) >> 3;                  // edges per wave (contiguous span)
    int ps = rb + wv * per;
    int pe = ps + per;
    if (ps > re) ps = re;
    if (pe > re) pe = re;

#pragma unroll 1
    for (int p = ps; p < pe; p += 8) {
        int cnt = pe - p;                      // wave-uniform, >= 1
        int rows[8]; float scales[8]; int dls[8];
#pragma unroll
        for (int k = 0; k < 8; ++k) {
            int q = (k < cnt) ? (p + k) : (pe - 1);   // clamp: dup last edge
            PackedEdge rec = packed[q];
            rows[k] = rec.row;
            scales[k] = (k < cnt) ? rec.scale : 0.f;  // zero-scale the dups
            dls[k] = pdst[q] - t0;
        }
        float hx[8], hy[8];
#pragma unroll
        for (int k = 0; k < 8; ++k) {
            const float* hp = h + (size_t)(rows[k] >> 3) * FEAT;
            hx[k] = hp[lane];
            hy[k] = hp[lane + 64];
        }
#pragma unroll
        for (int k = 0; k < 8; ++k) {
            int dl = dls[k];
            int sw = dl & 7;
            int base = dl << 10;
            int kk1 = (rows[k] & 7) * FEAT + lane;       // feats l
            int kk2 = kk1 + 64;                          // feats l+64
            int idx1 = base + ((((kk1 >> 2) ^ sw) << 2) | (kk1 & 3));
            int idx2 = base + ((((kk2 >> 2) ^ sw) << 2) | (kk2 & 3));
            atomicAdd(&agg[idx1], hx[k] * scales[k]);
            atomicAdd(&agg[idx2], hy[k] * scales[k]);
        }
    }
    __syncthreads();

    // ---------------- Phase B ----------------
    const int l15 = lane & 15;
    const int lhi = lane >> 4;
    f32x4 acc = (f32x4){0.f, 0.f, 0.f, 0.f};
    const bf16_t* wbase = wt + (size_t)(wv * 16 + l15) * (NRELS * FEAT);
    const float* arow = agg + (l15 << 10);
    const int swz = l15 & 7;
#pragma unroll 4
    for (int ks = 0; ks < 32; ++ks) {
        bf16x8_t af = *reinterpret_cast<const bf16x8_t*>(wbase + ks * 32 + lhi * 8);
        int c = ks * 8 + lhi * 2;                        // chunk pair c, c+1
        float4 v0 = *reinterpret_cast<const float4*>(arow + ((c ^ swz) << 2));
        float4 v1 = *reinterpret_cast<const float4*>(arow + (((c + 1) ^ swz) << 2));
        bf16x8_t bf;
        bf[0] = (bf16_t)v0.x; bf[1] = (bf16_t)v0.y;
        bf[2] = (bf16_t)v0.z; bf[3] = (bf16_t)v0.w;
        bf[4] = (bf16_t)v1.x; bf[5] = (bf16_t)v1.y;
        bf[6] = (bf16_t)v1.z; bf[7] = (bf16_t)v1.w;
        acc = __builtin_amdgcn_mfma_f32_16x16x32_bf16(af, bf, acc, 0, 0, 0);
    }

    // C/D: col = l15 = node-offset, row = lhi*4+i = fout-offset (m89-verified)
    int node = t0 + l15;
    if (node < nnodes) {
        float4 o;
        o.x = fmaxf(acc[0], 0.f);
        o.y = fmaxf(acc[1], 0.f);
        o.z = fmaxf(acc[2], 0.f);
        o.w = fmaxf(acc[3], 0.f);
        *reinterpret_cast<float4*>(out + (size_t)node * FEAT + wv * 16 + lhi * 4) = o;
    }
}

// ---------------------------------------------------------------------------
extern "C" void kernel_launch(void* const* d_in, const int* in_sizes, int n_in,
                              void* d_out, int out_size, void* d_ws, size_t ws_size,
                              hipStream_t stream) {
    const float* h = (const float*)d_in[0];
    const float* w = (const float*)d_in[1];
    const float* gw = (const float*)d_in[2];
    const float* nrm = (const float*)d_in[3];
    const int* src = (const int*)d_in[4];
    const int* dst = (const int*)d_in[5];
    const int* rel = (const int*)d_in[6];
    float* out = (float*)d_out;

    const int N = in_sizes[0] / FEAT;
    const int E = in_sizes[4];
    const int nb = (N + SCAN_CHUNK - 1) / SCAN_CHUNK;

    char* ws = (char*)d_ws;
    size_t off = 0;
    bf16_t* wt = (bf16_t*)(ws + off);
    off += align256((size_t)NRELS * FEAT * FEAT * sizeof(bf16_t));   // 256 KiB
    float* sg = (float*)(ws + off);
    off += align256((size_t)N * NRELS * sizeof(float));              // 3.2 MB
    int* deg = (int*)(ws + off);
    off += align256((size_t)N * sizeof(int));                        // 0.4 MB
    int* rowptr = (int*)(ws + off);
    off += align256((size_t)(N + 1) * sizeof(int));                  // 0.4 MB
    int* cursor = (int*)(ws + off);
    off += align256((size_t)N * sizeof(int));                        // 0.4 MB
    int* bsum = (int*)(ws + off);
    off += align256((size_t)nb * sizeof(int));
    PackedEdge* packed = (PackedEdge*)(ws + off);
    off += align256((size_t)E * sizeof(PackedEdge));                 // 4.8 MB
    int* pdst = (int*)(ws + off);
    off += align256((size_t)E * sizeof(int));                        // 2.4 MB

    k_convert_w<<<(NRELS * FEAT * FEAT + 255) / 256, 256, 0, stream>>>(w, wt);
    k_gate<<<(N + 3) / 4, 256, 0, stream>>>(h, gw, sg, N);
    hipMemsetAsync(deg, 0, (size_t)N * sizeof(int), stream);
    k_degree<<<(E + 255) / 256, 256, 0, stream>>>(dst, deg, E);
    k_scan_block<<<nb, 256, 0, stream>>>(deg, rowptr, bsum, N);
    k_scan_tops<<<1, 1024, 0, stream>>>(bsum, nb, rowptr + N);
    k_scan_add<<<(N + 255) / 256, 256, 0, stream>>>(rowptr, cursor, bsum, N);
    k_fill<<<(E + 255) / 256, 256, 0, stream>>>(src, dst, rel, nrm, sg, cursor,
                                                packed, pdst, E);
    k_fused<<<(N + 15) / 16, 512, 0, stream>>>(h, wt, packed, pdst, rowptr, out, N);
}

// Round 7
// 474.268 us; speedup vs baseline: 1.8048x; 1.8048x over previous
//
#include <hip/hip_runtime.h>
#include <hip/hip_bf16.h>

#define FEAT 128
#define NRELS 8
#define SCAN_CHUNK 256

typedef __bf16 bf16_t;
typedef __bf16 bf16x2_t __attribute__((ext_vector_type(2)));
typedef __bf16 bf16x8_t __attribute__((ext_vector_type(8)));
typedef float f32x4 __attribute__((ext_vector_type(4)));

struct __align__(8) PackedEdge { int row; float scale; };  // row = src*8 + rel

static inline size_t align256(size_t x) { return (x + 255) & ~(size_t)255; }

// ---------------------------------------------------------------------------
// W [r][d][f] fp32 -> Wt [f][r*128+d] bf16  (A-operand: m=fout rows, k=r*128+d
// contiguous per row -> 16B vector loads of 8 k-elements).
__global__ void k_convert_w(const float* __restrict__ w, bf16_t* __restrict__ wt) {
    int i = blockIdx.x * blockDim.x + threadIdx.x;
    if (i >= NRELS * FEAT * FEAT) return;
    int r = i >> 14;
    int rem = i & 16383;
    int d = rem >> 7;
    int f = rem & 127;
    wt[(size_t)f * (NRELS * FEAT) + r * FEAT + d] = (bf16_t)w[i];
}

// ---------------------------------------------------------------------------
// Gate: sg[n][r] = sigmoid(sum_d h[n][d]*gw[r][d]); fp32. One wave per node.
__global__ void k_gate(const float* __restrict__ h, const float* __restrict__ gw,
                       float* __restrict__ sg, int ncount) {
    int wv = (int)((blockIdx.x * blockDim.x + threadIdx.x) >> 6);
    int lane = threadIdx.x & 63;
    if (wv >= ncount) return;
    float2 hv = *reinterpret_cast<const float2*>(h + (size_t)wv * FEAT + lane * 2);
    float res[NRELS];
#pragma unroll
    for (int r = 0; r < NRELS; ++r) {
        float2 wvv = *reinterpret_cast<const float2*>(gw + r * FEAT + lane * 2);
        float s = hv.x * wvv.x + hv.y * wvv.y;
#pragma unroll
        for (int off = 32; off; off >>= 1) s += __shfl_xor(s, off, 64);
        res[r] = s;
    }
    if (lane == 0) {
#pragma unroll
        for (int r = 0; r < NRELS; ++r)
            sg[(size_t)wv * NRELS + r] = 1.0f / (1.0f + __expf(-res[r]));
    }
}

// ---------------------------------------------------------------------------
// CSR build over dst
__global__ void k_degree(const int* __restrict__ dstv, int* __restrict__ deg, int nedges) {
    int e = blockIdx.x * blockDim.x + threadIdx.x;
    if (e >= nedges) return;
    atomicAdd(&deg[dstv[e]], 1);
}

__global__ __launch_bounds__(256) void k_scan_block(const int* __restrict__ in,
                                                    int* __restrict__ outv,
                                                    int* __restrict__ bsum, int n) {
    __shared__ int sm[256];
    int t = threadIdx.x;
    int idx = blockIdx.x * SCAN_CHUNK + t;
    int v = (idx < n) ? in[idx] : 0;
    sm[t] = v;
    __syncthreads();
    for (int off = 1; off < 256; off <<= 1) {
        int x = (t >= off) ? sm[t - off] : 0;
        __syncthreads();
        sm[t] += x;
        __syncthreads();
    }
    if (idx < n) outv[idx] = sm[t] - v;
    if (t == 255) bsum[blockIdx.x] = sm[255];
}

__global__ __launch_bounds__(1024) void k_scan_tops(int* __restrict__ bsum, int nb) {
    __shared__ int sm[1024];
    int t = threadIdx.x;
    if (nb <= 1024) {
        int v = (t < nb) ? bsum[t] : 0;
        sm[t] = v;
        __syncthreads();
        for (int off = 1; off < 1024; off <<= 1) {
            int x = (t >= off) ? sm[t - off] : 0;
            __syncthreads();
            sm[t] += x;
            __syncthreads();
        }
        if (t < nb) bsum[t] = sm[t] - v;
    } else if (t == 0) {
        int run = 0;
        for (int b = 0; b < nb; ++b) { int v = bsum[b]; bsum[b] = run; run += v; }
    }
}

__global__ void k_scan_add(int* __restrict__ rowptr, const int* __restrict__ bsum, int n) {
    int i = blockIdx.x * blockDim.x + threadIdx.x;
    if (i >= n) return;
    rowptr[i] += bsum[i >> 8];
}

// Fill packed records {row=src*8+rel, scale} at CSR slots, bumping rowptr in
// place. Post-condition: rowptr[d] == original rowptr[d+1], so consumers use
// beg = (d ? rowptr[d-1] : 0), end = rowptr[d].
__global__ void k_fill(const int* __restrict__ src, const int* __restrict__ dstv,
                       const int* __restrict__ rel, const float* __restrict__ nrm,
                       const float* __restrict__ sg, int* __restrict__ rowptr,
                       PackedEdge* __restrict__ packed, int nedges) {
    int e = blockIdx.x * blockDim.x + threadIdx.x;
    if (e >= nedges) return;
    int d = dstv[e];
    int s = src[e];
    int r = rel[e];
    int pos = atomicAdd(&rowptr[d], 1);
    PackedEdge p;
    p.row = s * NRELS + r;
    p.scale = nrm[e] * sg[(size_t)s * NRELS + r];
    packed[pos] = p;
}

// ---------------------------------------------------------------------------
// Fused aggregate + transform. Block = 1024 threads = 16 waves = 16 dst nodes.
// Phase A: wave wv owns node t0+wv; walks its CSR edge span with a depth-2
//   load pipeline (round-3-gather shape: the only Phase-A structure measured
//   fast). Lane l accumulates feats {2l,2l+1} x 8 rels in fp32 registers.
//   Then ONE round of plain swizzled ds_write_b32 into agg[16][1024] bf16
//   (chunk c = k>>3 stored at c^(node&7) -> every access 2 lanes/bank = free).
// Phase B: waves 0..7: out[node=t0+l15][fout=wv*16+lhi*4+i], K=1024 in 32
//   mfma_16x16x32_bf16 steps; A=Wt (global, L2-hot 256KB), B=agg from LDS via
//   ds_read_b128. Fused ReLU, float4 stores. Waves 8..15 exit after the sync.
__global__ __launch_bounds__(1024, 8) void k_fused(const float* __restrict__ h,
                                                   const bf16_t* __restrict__ wt,
                                                   const PackedEdge* __restrict__ packed,
                                                   const int* __restrict__ rowptr,
                                                   float* __restrict__ out, int nnodes) {
    __shared__ bf16_t agg[16 * 1024];          // 32 KiB -> 2 blocks/CU
    const int t0 = blockIdx.x * 16;
    const int wv = threadIdx.x >> 6;
    const int lane = threadIdx.x & 63;
    const int node = t0 + wv;

    // ---------------- Phase A ----------------
    float ax[NRELS], ay[NRELS];
#pragma unroll
    for (int r = 0; r < NRELS; ++r) { ax[r] = 0.f; ay[r] = 0.f; }

    if (node < nnodes) {
        int beg = node > 0 ? rowptr[node - 1] : 0;   // post-fill semantics
        int end = rowptr[node];
        PackedEdge p0, p1;
        float2 h0, h1;
        p0.row = 0; p0.scale = 0.f; p1 = p0;
        h0 = make_float2(0.f, 0.f); h1 = h0;
        if (beg < end) {
            p0 = packed[beg];
            h0 = *reinterpret_cast<const float2*>(h + (size_t)(p0.row >> 3) * FEAT + lane * 2);
        }
        if (beg + 1 < end) {
            p1 = packed[beg + 1];
            h1 = *reinterpret_cast<const float2*>(h + (size_t)(p1.row >> 3) * FEAT + lane * 2);
        }
#pragma unroll 1
        for (int j = beg; j < end; ++j) {
            PackedEdge p2; float2 h2;
            p2.row = 0; p2.scale = 0.f; h2 = make_float2(0.f, 0.f);
            if (j + 2 < end) {
                p2 = packed[j + 2];
                h2 = *reinterpret_cast<const float2*>(h + (size_t)(p2.row >> 3) * FEAT + lane * 2);
            }
            int rl = p0.row & 7;
            float s = p0.scale;
#pragma unroll
            for (int r = 0; r < NRELS; ++r) {
                float sr = (rl == r) ? s : 0.f;
                ax[r] = fmaf(h0.x, sr, ax[r]);
                ay[r] = fmaf(h0.y, sr, ay[r]);
            }
            p0 = p1; h0 = h1;
            p1 = p2; h1 = h2;
        }
    }

    // Flush registers -> swizzled LDS row (full row always written: zeros for
    // OOB/zero-degree nodes keep Phase B reads clean).
    {
        const int sw = wv & 7;
        bf16_t* rowp = agg + (wv << 10);
#pragma unroll
        for (int r = 0; r < NRELS; ++r) {
            int k = r * FEAT + lane * 2;
            int chunk = k >> 3;                       // r*16 + (lane>>2)
            int off = ((chunk ^ sw) << 3) | (k & 7);
            bf16x2_t v;
            v.x = (bf16_t)ax[r];
            v.y = (bf16_t)ay[r];
            *reinterpret_cast<bf16x2_t*>(rowp + off) = v;
        }
    }
    __syncthreads();

    // ---------------- Phase B ----------------
    if (wv < 8) {
        const int l15 = lane & 15;
        const int lhi = lane >> 4;
        f32x4 acc = (f32x4){0.f, 0.f, 0.f, 0.f};
        const bf16_t* wbase = wt + (size_t)(wv * 16 + l15) * (NRELS * FEAT);
        const bf16_t* arow = agg + (l15 << 10);
        const int swz = l15 & 7;
#pragma unroll 4
        for (int ks = 0; ks < 32; ++ks) {
            bf16x8_t af = *reinterpret_cast<const bf16x8_t*>(wbase + ks * 32 + lhi * 8);
            int c = ks * 4 + lhi;
            bf16x8_t bf = *reinterpret_cast<const bf16x8_t*>(arow + ((c ^ swz) << 3));
            acc = __builtin_amdgcn_mfma_f32_16x16x32_bf16(af, bf, acc, 0, 0, 0);
        }
        // C/D: col = l15 = node-offset, row = lhi*4+i = fout-offset (m89-verified)
        int nodeo = t0 + l15;
        if (nodeo < nnodes) {
            float4 o;
            o.x = fmaxf(acc[0], 0.f);
            o.y = fmaxf(acc[1], 0.f);
            o.z = fmaxf(acc[2], 0.f);
            o.w = fmaxf(acc[3], 0.f);
            *reinterpret_cast<float4*>(out + (size_t)nodeo * FEAT + wv * 16 + lhi * 4) = o;
        }
    }
}

// ---------------------------------------------------------------------------
extern "C" void kernel_launch(void* const* d_in, const int* in_sizes, int n_in,
                              void* d_out, int out_size, void* d_ws, size_t ws_size,
                              hipStream_t stream) {
    const float* h = (const float*)d_in[0];
    const float* w = (const float*)d_in[1];
    const float* gw = (const float*)d_in[2];
    const float* nrm = (const float*)d_in[3];
    const int* src = (const int*)d_in[4];
    const int* dst = (const int*)d_in[5];
    const int* rel = (const int*)d_in[6];
    float* out = (float*)d_out;

    const int N = in_sizes[0] / FEAT;
    const int E = in_sizes[4];
    const int nb = (N + SCAN_CHUNK - 1) / SCAN_CHUNK;

    char* ws = (char*)d_ws;
    size_t off = 0;
    bf16_t* wt = (bf16_t*)(ws + off);
    off += align256((size_t)NRELS * FEAT * FEAT * sizeof(bf16_t));   // 256 KiB
    float* sg = (float*)(ws + off);
    off += align256((size_t)N * NRELS * sizeof(float));              // 3.2 MB
    int* deg = (int*)(ws + off);
    off += align256((size_t)N * sizeof(int));                        // 0.4 MB
    int* rowptr = (int*)(ws + off);
    off += align256((size_t)(N + 1) * sizeof(int));                  // 0.4 MB
    int* bsum = (int*)(ws + off);
    off += align256((size_t)nb * sizeof(int));
    PackedEdge* packed = (PackedEdge*)(ws + off);
    off += align256((size_t)E * sizeof(PackedEdge));                 // 4.8 MB

    k_convert_w<<<(NRELS * FEAT * FEAT + 255) / 256, 256, 0, stream>>>(w, wt);
    k_gate<<<(N + 3) / 4, 256, 0, stream>>>(h, gw, sg, N);
    hipMemsetAsync(deg, 0, (size_t)N * sizeof(int), stream);
    k_degree<<<(E + 255) / 256, 256, 0, stream>>>(dst, deg, E);
    k_scan_block<<<nb, 256, 0, stream>>>(deg, rowptr, bsum, N);
    k_scan_tops<<<1, 1024, 0, stream>>>(bsum, nb);
    k_scan_add<<<(N + 255) / 256, 256, 0, stream>>>(rowptr, bsum, N);
    k_fill<<<(E + 255) / 256, 256, 0, stream>>>(src, dst, rel, nrm, sg, rowptr,
                                                packed, E);
    k_fused<<<(N + 15) / 16, 1024, 0, stream>>>(h, wt, packed, rowptr, out, N);
}